// Round 3
// baseline (320.598 us; speedup 1.0000x reference)
//
#include <hip/hip_runtime.h>
#include <hip/hip_bf16.h>

using bf16 = __hip_bfloat16;

typedef __attribute__((ext_vector_type(8))) __bf16 bf16x8;
typedef __attribute__((ext_vector_type(4))) float floatx4;

#define EPS 1e-6f

// ---------------------------------------------------------------------------
// async global->LDS, 16B per lane
// ---------------------------------------------------------------------------
__device__ __forceinline__ void load_lds16(const void* g, void* l) {
    __builtin_amdgcn_global_load_lds(
        (const __attribute__((address_space(1))) void*)g,
        (__attribute__((address_space(3))) void*)l, 16, 0, 0);
}

__device__ __forceinline__ void storeOut(float* p, float v) { *p = v; }
__device__ __forceinline__ void storeOut(bf16* p, float v) { *p = __float2bfloat16(v); }

// ---------------------------------------------------------------------------
// Canonical NT GEMM: D[m][n] = sum_k A[m][k] * B[n][k]
// BM=BN=128, BK=64. 256 threads = 4 waves 2x2, wave = 64x64 (4x4 MFMA 16x16x32).
// 1-D grid with XCD-aware decode: id&7 = XCD slot, each XCD owns a contiguous
// (z, tile) range so its L2 caches ~Z/8 batches' operands.
// tpbShift: log2(tiles per batch); gxShift: log2(x-tiles).
// BIAS_MODE: 0 none, 1 along m, 2 along n.
// SCALE_EN: v *= scale (before EXP).
// EXP_MODE: v = exp(v); accumulate row sums into rowsum[z*rsStride+row] (atomic).
// ROWDIV:   v *= 1/rowsum[z*rsStride+row].
// RESID_EN: v += resid[z*rStride + m*ldr + n] (fp32).
// ---------------------------------------------------------------------------
template <int BIAS_MODE, int SCALE_EN, int RESID_EN, int EXP_MODE, int ROWDIV,
          typename OutT>
__global__ __launch_bounds__(256) void gemm_nt(
    const bf16* __restrict__ A, long long aStride, int lda,
    const bf16* __restrict__ B, long long bStride, int ldb,
    OutT* __restrict__ D, long long dStride, int ldd,
    const float* __restrict__ bias,
    const float* __restrict__ resid, long long rStride, int ldr,
    float* __restrict__ rowsum, int rsStride,
    int K, float scale, int tpbShift, int gxShift)
{
    __shared__ bf16 As[128 * 64];   // 16 KB
    __shared__ bf16 Bs[128 * 64];   // 16 KB

    // XCD-aware swizzle: consecutive blockIdx round-robin across 8 XCDs, so
    // giving XCD j the j-th contiguous chunk of work clusters each XCD's
    // working set (same z / shared tiles) into its own L2.
    const int chunk = gridDim.x >> 3;
    const int glob  = (blockIdx.x & 7) * chunk + (blockIdx.x >> 3);
    const int z  = glob >> tpbShift;
    const int t  = glob & ((1 << tpbShift) - 1);
    const int m0 = (t >> gxShift) << 7;
    const int n0 = (t & ((1 << gxShift) - 1)) << 7;

    const int tid  = threadIdx.x;
    const int lane = tid & 63;
    const int wave = tid >> 6;
    const int wm   = wave >> 1;      // 0..1
    const int wn   = wave & 1;       // 0..1

    const bf16* Ab = A + (size_t)z * aStride + (size_t)m0 * lda;
    const bf16* Bb = B + (size_t)z * bStride + (size_t)n0 * ldb;

    floatx4 acc[4][4];
#pragma unroll
    for (int i = 0; i < 4; ++i)
#pragma unroll
        for (int j = 0; j < 4; ++j) acc[i][j] = (floatx4){0.f, 0.f, 0.f, 0.f};

    // LDS: 16B slot idx = kq*128 + row (kq = k-chunk of 8 bf16, 0..7)
    const char* AsB = (const char*)As;
    const char* BsB = (const char*)Bs;
    const int laneRow = lane & 15;
    const int laneKq  = lane >> 4;

    const int kIters = K >> 6;
    for (int kt = 0; kt < kIters; ++kt) {
        const int k0 = kt << 6;
#pragma unroll
        for (int t4 = 0; t4 < 4; ++t4) {
            const int idx = tid + t4 * 256;
            const int r = idx & 127, q = idx >> 7;   // q 0..7
            load_lds16(Ab + (size_t)r * lda + k0 + q * 8, (char*)As + idx * 16);
            load_lds16(Bb + (size_t)r * ldb + k0 + q * 8, (char*)Bs + idx * 16);
        }
        __syncthreads();

#pragma unroll
        for (int s = 0; s < 2; ++s) {
            const int kqBase = s * 4 + laneKq;
            bf16x8 af[4], bfr[4];
#pragma unroll
            for (int im = 0; im < 4; ++im)
                af[im] = *(const bf16x8*)(AsB +
                    (kqBase * 128 + wm * 64 + im * 16 + laneRow) * 16);
#pragma unroll
            for (int in = 0; in < 4; ++in)
                bfr[in] = *(const bf16x8*)(BsB +
                    (kqBase * 128 + wn * 64 + in * 16 + laneRow) * 16);
#pragma unroll
            for (int im = 0; im < 4; ++im)
#pragma unroll
                for (int in = 0; in < 4; ++in)
                    acc[im][in] = __builtin_amdgcn_mfma_f32_16x16x32_bf16(
                        af[im], bfr[in], acc[im][in], 0, 0, 0);
        }
        __syncthreads();
    }

    // Epilogue. D frag layout: col = lane&15, row = (lane>>4)*4 + reg
    const size_t dbase = (size_t)z * dStride;
#pragma unroll
    for (int im = 0; im < 4; ++im) {
        const int gmb = m0 + wm * 64 + im * 16 + (laneKq << 2);
        float ri[4];
        if (ROWDIV) {
#pragma unroll
            for (int r = 0; r < 4; ++r)
                ri[r] = 1.f / rowsum[(size_t)z * rsStride + gmb + r];
        }
        float rsum[4] = {0.f, 0.f, 0.f, 0.f};
#pragma unroll
        for (int in = 0; in < 4; ++in) {
            const int gn = n0 + wn * 64 + in * 16 + laneRow;
            float bn = 0.f;
            if (BIAS_MODE == 2) bn = bias[gn];
#pragma unroll
            for (int r = 0; r < 4; ++r) {
                const int gm = gmb + r;
                float v = acc[im][in][r];
                if (SCALE_EN) v *= scale;
                if (EXP_MODE) { v = __expf(v); rsum[r] += v; }
                if (ROWDIV) v *= ri[r];
                if (BIAS_MODE == 1) v += bias[gm];
                if (BIAS_MODE == 2) v += bn;
                if (RESID_EN)
                    v += resid[(size_t)z * rStride + (size_t)gm * ldr + gn];
                storeOut(D + dbase + (size_t)gm * ldd + gn, v);
            }
        }
        if (EXP_MODE) {
#pragma unroll
            for (int r = 0; r < 4; ++r) {
                float s = rsum[r];
                s += __shfl_xor(s, 1);
                s += __shfl_xor(s, 2);
                s += __shfl_xor(s, 4);
                s += __shfl_xor(s, 8);
                if (laneRow == 0)
                    atomicAdd(rowsum + (size_t)z * rsStride + gmb + r, s);
            }
        }
    }
}

// ---------------------------------------------------------------------------
// GroupNorm stats: one block per (b, g); 16 ch x 1024 = 16384 contiguous floats
// ---------------------------------------------------------------------------
__global__ __launch_bounds__(256) void gn_stats(const float* __restrict__ x,
                                                float* __restrict__ stats)
{
    const int bg = blockIdx.x;
    const float4* p = (const float4*)(x + (size_t)bg * 16384);
    float s = 0.f, ss = 0.f;
    for (int i = threadIdx.x; i < 4096; i += 256) {
        float4 v = p[i];
        s  += v.x + v.y + v.z + v.w;
        ss += v.x * v.x + v.y * v.y + v.z * v.z + v.w * v.w;
    }
#pragma unroll
    for (int off = 32; off; off >>= 1) {
        s  += __shfl_down(s, off);
        ss += __shfl_down(ss, off);
    }
    __shared__ float rs[4], rss[4];
    const int wv = threadIdx.x >> 6;
    if ((threadIdx.x & 63) == 0) { rs[wv] = s; rss[wv] = ss; }
    __syncthreads();
    if (threadIdx.x == 0) {
        float S  = rs[0] + rs[1] + rs[2] + rs[3];
        float SS = rss[0] + rss[1] + rss[2] + rss[3];
        float mean = S * (1.f / 16384.f);
        float var  = SS * (1.f / 16384.f) - mean * mean;
        stats[2 * bg]     = mean;
        stats[2 * bg + 1] = rsqrtf(var + EPS);
    }
}

// ---------------------------------------------------------------------------
// GN apply + transpose: x (B,512,1024) fp32 -> xnT (B,1024,512) bf16
// ---------------------------------------------------------------------------
__global__ __launch_bounds__(256) void gn_apply_t(const float* __restrict__ x,
                                                  const float* __restrict__ stats,
                                                  const float* __restrict__ gamma,
                                                  const float* __restrict__ beta,
                                                  bf16* __restrict__ xnT)
{
    __shared__ bf16 tile[32][36];
    const int b = blockIdx.z, c0 = blockIdx.y * 32, i0 = blockIdx.x * 32;
    {
        const int cc = threadIdx.x >> 3;
        const int i4 = (threadIdx.x & 7) << 2;
        const int c  = c0 + cc;
        const float mean = stats[2 * ((b << 5) + (c >> 4))];
        const float rstd = stats[2 * ((b << 5) + (c >> 4)) + 1];
        const float a  = gamma[c] * rstd;
        const float bb = beta[c] - mean * a;
        float4 v = *(const float4*)(x + (((size_t)(b * 512 + c)) << 10) + i0 + i4);
        tile[cc][i4 + 0] = __float2bfloat16(v.x * a + bb);
        tile[cc][i4 + 1] = __float2bfloat16(v.y * a + bb);
        tile[cc][i4 + 2] = __float2bfloat16(v.z * a + bb);
        tile[cc][i4 + 3] = __float2bfloat16(v.w * a + bb);
    }
    __syncthreads();
    {
        const int ii = threadIdx.x >> 3;
        const int c4 = (threadIdx.x & 7) << 2;
        union { bf16 h[4]; uint2 u; } pk;
        pk.h[0] = tile[c4 + 0][ii];
        pk.h[1] = tile[c4 + 1][ii];
        pk.h[2] = tile[c4 + 2][ii];
        pk.h[3] = tile[c4 + 3][ii];
        *((uint2*)(xnT + (((size_t)(b * 1024 + i0 + ii)) << 9) + c0 + c4)) = pk.u;
    }
}

// ---------------------------------------------------------------------------
// fp32 -> bf16 convert (n4 float4 groups)
// ---------------------------------------------------------------------------
__global__ __launch_bounds__(256) void cvt_bf16(const float* __restrict__ s,
                                                bf16* __restrict__ d, int n4)
{
    const int i = blockIdx.x * 256 + threadIdx.x;
    if (i < n4) {
        float4 v = ((const float4*)s)[i];
        union { bf16 h[4]; uint2 u; } pk;
        pk.h[0] = __float2bfloat16(v.x);
        pk.h[1] = __float2bfloat16(v.y);
        pk.h[2] = __float2bfloat16(v.z);
        pk.h[3] = __float2bfloat16(v.w);
        ((uint2*)d)[i] = pk.u;
    }
}

// ---------------------------------------------------------------------------
extern "C" void kernel_launch(void* const* d_in, const int* in_sizes, int n_in,
                              void* d_out, int out_size, void* d_ws, size_t ws_size,
                              hipStream_t stream)
{
    const float* x     = (const float*)d_in[0];
    const float* gamma = (const float*)d_in[1];
    const float* beta  = (const float*)d_in[2];
    const float* wq    = (const float*)d_in[3];
    const float* bq    = (const float*)d_in[4];
    const float* wk    = (const float*)d_in[5];
    const float* bk    = (const float*)d_in[6];
    const float* wv    = (const float*)d_in[7];
    const float* bv    = (const float*)d_in[8];
    const float* wp    = (const float*)d_in[9];
    const float* bp    = (const float*)d_in[10];
    float* out = (float*)d_out;

    char* ws = (char*)d_ws;
    size_t off = 0;
    auto alloc = [&](size_t bytes) -> char* {
        char* p = ws + off;
        off += (bytes + 255) & ~(size_t)255;
        return p;
    };

    const long long S  = 1024, C = 512;
    const long long BS = S * C;           // elements per batch of x/q/v/...
    const long long ES = S * S;           // elements per batch of P/qkT

    float* stats = (float*)alloc(512 * 2 * sizeof(float));
    float* bqk   = (float*)alloc(1024 * sizeof(float));
    float* rowsum = (float*)alloc((size_t)16 * S * sizeof(float));
    bf16* wqkb = (bf16*)alloc((size_t)2 * C * C * 2);   // [wq; wk] rows
    bf16* wvb  = (bf16*)alloc((size_t)C * C * 2);
    bf16* wpb  = (bf16*)alloc((size_t)C * C * 2);
    bf16* xnT  = (bf16*)alloc((size_t)16 * BS * 2);
    bf16* qkT  = (bf16*)alloc((size_t)16 * ES * 2);     // (B,1024,1024): [qT|kT]
    bf16* vv   = (bf16*)alloc((size_t)16 * BS * 2);
    bf16* O2   = (bf16*)alloc((size_t)16 * BS * 2);

    // P (bf16) chunked by batch if workspace tight
    int CB = 16;
    while (CB > 1 && off + (size_t)CB * ES * 2 + 1024 > ws_size) CB >>= 1;
    bf16* P = (bf16*)alloc((size_t)CB * ES * 2);

    // weights fp32 -> bf16 ([wq;wk] concatenated), biases concat
    cvt_bf16<<<256, 256, 0, stream>>>(wq, wqkb, 65536);
    cvt_bf16<<<256, 256, 0, stream>>>(wk, wqkb + (size_t)C * C, 65536);
    cvt_bf16<<<256, 256, 0, stream>>>(wv, wvb, 65536);
    cvt_bf16<<<256, 256, 0, stream>>>(wp, wpb, 65536);
    hipMemcpyAsync(bqk, bq, 512 * sizeof(float), hipMemcpyDeviceToDevice, stream);
    hipMemcpyAsync(bqk + 512, bk, 512 * sizeof(float), hipMemcpyDeviceToDevice, stream);
    hipMemsetAsync(rowsum, 0, (size_t)16 * S * sizeof(float), stream);

    // GroupNorm
    gn_stats<<<512, 256, 0, stream>>>(x, stats);
    gn_apply_t<<<dim3(32, 16, 16), 256, 0, stream>>>(x, stats, gamma, beta, xnT);

    // qkT[i][o] = sum_c xnT[i][c] Wqk[o][c] + bqk[o]  (M=1024,N=1024,K=512,Z=16)
    gemm_nt<2, 0, 0, 0, 0, bf16><<<1024, 256, 0, stream>>>(
        xnT, BS, 512, wqkb, 0, 512, qkT, ES, 1024,
        bqk, nullptr, 0, 0, nullptr, 0, 512, 1.f, /*tpb*/6, /*gx*/3);
    // v[o][j] = sum_c Wv[o][c] xnT[j][c] + bv[o]      (M=512,N=1024,K=512,Z=16)
    gemm_nt<1, 0, 0, 0, 0, bf16><<<512, 256, 0, stream>>>(
        wvb, 0, 512, xnT, BS, 512, vv, BS, 1024,
        bv, nullptr, 0, 0, nullptr, 0, 512, 1.f, /*tpb*/5, /*gx*/3);

    const float scale = 0.044194173824159216f; // 512^-0.5
    for (int b0 = 0; b0 < 16; b0 += CB) {
        // P[i][j] = exp(scale * sum_c qT[i][c] kT[j][c]); rowsum[i] += ...
        gemm_nt<0, 1, 0, 1, 0, bf16><<<CB * 64, 256, 0, stream>>>(
            qkT + (size_t)b0 * ES, ES, 1024,
            qkT + (size_t)b0 * ES + 512, ES, 1024,
            P, ES, 1024,
            nullptr, nullptr, 0, 0, rowsum + (size_t)b0 * S, (int)S,
            512, scale, /*tpb*/6, /*gx*/3);
        // O2[i][c] = (sum_j P[i][j] v[c][j]) / rowsum[i]  (M=1024,N=512,K=1024)
        gemm_nt<0, 0, 0, 0, 1, bf16><<<CB * 32, 256, 0, stream>>>(
            P, ES, 1024,
            vv + (size_t)b0 * BS, BS, 1024,
            O2 + (size_t)b0 * BS, BS, 512,
            nullptr, nullptr, 0, 0, rowsum + (size_t)b0 * S, (int)S,
            1024, 1.f, /*tpb*/5, /*gx*/2);
    }

    // out[o][i] = sum_c wp[o][c] O2[i][c] + bp[o] + x[o][i]  (M=512,N=1024,K=512)
    gemm_nt<1, 0, 1, 0, 0, float><<<512, 256, 0, stream>>>(
        wpb, 0, 512, O2, BS, 512, out, BS, 1024,
        bp, x, BS, 1024, nullptr, 0, 512, 1.f, /*tpb*/5, /*gx*/3);
}

// Round 4
// 293.418 us; speedup vs baseline: 1.0926x; 1.0926x over previous
//
#include <hip/hip_runtime.h>
#include <hip/hip_bf16.h>

using bf16 = __hip_bfloat16;

typedef __attribute__((ext_vector_type(8))) __bf16 bf16x8;
typedef __attribute__((ext_vector_type(4))) float floatx4;

#define EPS 1e-6f

// raw pipeline controls: memory clobber pins all memory ops (global_load_lds,
// ds_read) to their program-order side of these.
#define RAW_BARRIER()  asm volatile("s_barrier" ::: "memory")
#define WAIT_VM4()     asm volatile("s_waitcnt vmcnt(4)" ::: "memory")
#define WAIT_VM0()     asm volatile("s_waitcnt vmcnt(0)" ::: "memory")

__device__ __forceinline__ void load_lds16(const void* g, void* l) {
    __builtin_amdgcn_global_load_lds(
        (const __attribute__((address_space(1))) void*)g,
        (__attribute__((address_space(3))) void*)l, 16, 0, 0);
}

__device__ __forceinline__ void storeOut(float* p, float v) { *p = v; }
__device__ __forceinline__ void storeOut(bf16* p, float v) { *p = __float2bfloat16(v); }

// ---------------------------------------------------------------------------
// Canonical NT GEMM: D[m][n] = sum_k A[m][k] * B[n][k]
// BM=BN=128, BK=32, double-buffered LDS (2x8KB per operand), manual vmcnt
// pipeline: loads for iter t+1 stay in flight across iter t's barriers.
// 1-D grid, XCD-aware decode (id&7 = XCD slot -> contiguous work chunk).
// QKV: n0<1024 -> store D (qkT, i-major); n0>=1024 -> store transposed into
//      vout (vv[c][j]) with 8B packed stores.
// ---------------------------------------------------------------------------
template <int BIAS_MODE, int SCALE_EN, int RESID_EN, int EXP_MODE, int ROWDIV,
          int QKV, typename OutT>
__global__ __launch_bounds__(256) void gemm_nt(
    const bf16* __restrict__ A, long long aStride, int lda,
    const bf16* __restrict__ B, long long bStride, int ldb,
    OutT* __restrict__ D, long long dStride, int ldd,
    bf16* __restrict__ vout, long long vStride,
    const float* __restrict__ bias,
    const float* __restrict__ resid, long long rStride, int ldr,
    float* __restrict__ rowsum, int rsStride,
    int K, float scale, int tpb, int gx)
{
    __shared__ bf16 As[2][128 * 32];   // 2 x 8 KB
    __shared__ bf16 Bs[2][128 * 32];   // 2 x 8 KB

    // XCD-aware swizzle: blockIdx round-robins across 8 XCDs; give XCD j the
    // j-th contiguous chunk so its L2 holds a clustered working set.
    const unsigned chunk = gridDim.x >> 3;
    const unsigned glob  = (blockIdx.x & 7) * chunk + (blockIdx.x >> 3);
    const unsigned z  = glob / (unsigned)tpb;
    const unsigned t  = glob % (unsigned)tpb;
    const int m0 = (int)(t / (unsigned)gx) << 7;
    const int n0 = (int)(t % (unsigned)gx) << 7;

    const int tid  = threadIdx.x;
    const int lane = tid & 63;
    const int wave = tid >> 6;
    const int wm   = wave >> 1;
    const int wn   = wave & 1;

    const bf16* Ab = A + (size_t)z * aStride + (size_t)m0 * lda;
    const bf16* Bb = B + (size_t)z * bStride + (size_t)n0 * ldb;

    floatx4 acc[4][4];
#pragma unroll
    for (int i = 0; i < 4; ++i)
#pragma unroll
        for (int j = 0; j < 4; ++j) acc[i][j] = (floatx4){0.f, 0.f, 0.f, 0.f};

    const int laneRow = lane & 15;
    const int laneKq  = lane >> 4;
    // 16B slot idx = kq*128 + row; tid and tid+256 map directly to slots.
    const int r1 = tid & 127, q1 = tid >> 7;       // kq 0..1
    const int i2 = tid + 256;
    const int q2 = q1 + 2;                         // kq 2..3

    auto stage = [&](int kt) {
        const int k0 = kt << 5;
        char* Ad = (char*)As[kt & 1];
        char* Bd = (char*)Bs[kt & 1];
        load_lds16(Ab + (size_t)r1 * lda + k0 + q1 * 8, Ad + tid * 16);
        load_lds16(Ab + (size_t)r1 * lda + k0 + q2 * 8, Ad + i2 * 16);
        load_lds16(Bb + (size_t)r1 * ldb + k0 + q1 * 8, Bd + tid * 16);
        load_lds16(Bb + (size_t)r1 * ldb + k0 + q2 * 8, Bd + i2 * 16);
    };

    const int fragOff = ((laneKq * 128 + laneRow) * 16);
    const int kIters = K >> 5;

    stage(0);
    stage(1);
    for (int kt = 0; kt < kIters; ++kt) {
        if (kt + 1 < kIters) { WAIT_VM4(); } else { WAIT_VM0(); }
        RAW_BARRIER();

        const char* AsB = (const char*)As[kt & 1];
        const char* BsB = (const char*)Bs[kt & 1];
        bf16x8 af[4], bfr[4];
#pragma unroll
        for (int im = 0; im < 4; ++im)
            af[im] = *(const bf16x8*)(AsB + fragOff + (wm * 64 + im * 16) * 16);
#pragma unroll
        for (int in = 0; in < 4; ++in)
            bfr[in] = *(const bf16x8*)(BsB + fragOff + (wn * 64 + in * 16) * 16);
#pragma unroll
        for (int im = 0; im < 4; ++im)
#pragma unroll
            for (int in = 0; in < 4; ++in)
                acc[im][in] = __builtin_amdgcn_mfma_f32_16x16x32_bf16(
                    af[im], bfr[in], acc[im][in], 0, 0, 0);

        RAW_BARRIER();
        if (kt + 2 < kIters) stage(kt + 2);
    }

    // Epilogue. C/D frag layout: col = lane&15, row = (lane>>4)*4 + reg
    const size_t dbase = (size_t)z * dStride;
#pragma unroll
    for (int im = 0; im < 4; ++im) {
        const int gmb = m0 + wm * 64 + im * 16 + (laneKq << 2);
        float ri[4];
        if (ROWDIV) {
#pragma unroll
            for (int r = 0; r < 4; ++r)
                ri[r] = 1.f / rowsum[(size_t)z * rsStride + gmb + r];
        }
        float rsum[4] = {0.f, 0.f, 0.f, 0.f};
#pragma unroll
        for (int in = 0; in < 4; ++in) {
            const int gn = n0 + wn * 64 + in * 16 + laneRow;
            float bn = 0.f;
            if (BIAS_MODE == 2) bn = bias[gn];
            if (QKV && n0 >= 1024) {
                // transposed store into vv[c][j]: lane writes 4 consecutive j
                union { bf16 h[4]; ushort4 u; } pk;
#pragma unroll
                for (int r = 0; r < 4; ++r)
                    pk.h[r] = __float2bfloat16(acc[im][in][r] + bn);
                *(ushort4*)(vout + (size_t)z * vStride +
                            (size_t)(gn - 1024) * 1024 + gmb) = pk.u;
            } else {
#pragma unroll
                for (int r = 0; r < 4; ++r) {
                    const int gm = gmb + r;
                    float v = acc[im][in][r];
                    if (SCALE_EN) v *= scale;
                    if (EXP_MODE) { v = __expf(v); rsum[r] += v; }
                    if (ROWDIV) v *= ri[r];
                    if (BIAS_MODE == 1) v += bias[gm];
                    if (BIAS_MODE == 2) v += bn;
                    if (RESID_EN)
                        v += resid[(size_t)z * rStride + (size_t)gm * ldr + gn];
                    storeOut(D + dbase + (size_t)gm * ldd + gn, v);
                }
            }
        }
        if (EXP_MODE) {
#pragma unroll
            for (int r = 0; r < 4; ++r) {
                float s = rsum[r];
                s += __shfl_xor(s, 1);
                s += __shfl_xor(s, 2);
                s += __shfl_xor(s, 4);
                s += __shfl_xor(s, 8);
                if (laneRow == 0)
                    atomicAdd(rowsum + (size_t)z * rsStride + gmb + r, s);
            }
        }
    }
}

// ---------------------------------------------------------------------------
// GroupNorm stats: one block per (b, g); 16 ch x 1024 = 16384 contiguous floats
// ---------------------------------------------------------------------------
__global__ __launch_bounds__(256) void gn_stats(const float* __restrict__ x,
                                                float* __restrict__ stats)
{
    const int bg = blockIdx.x;
    const float4* p = (const float4*)(x + (size_t)bg * 16384);
    float s = 0.f, ss = 0.f;
    for (int i = threadIdx.x; i < 4096; i += 256) {
        float4 v = p[i];
        s  += v.x + v.y + v.z + v.w;
        ss += v.x * v.x + v.y * v.y + v.z * v.z + v.w * v.w;
    }
#pragma unroll
    for (int off = 32; off; off >>= 1) {
        s  += __shfl_down(s, off);
        ss += __shfl_down(ss, off);
    }
    __shared__ float rs[4], rss[4];
    const int wv = threadIdx.x >> 6;
    if ((threadIdx.x & 63) == 0) { rs[wv] = s; rss[wv] = ss; }
    __syncthreads();
    if (threadIdx.x == 0) {
        float S  = rs[0] + rs[1] + rs[2] + rs[3];
        float SS = rss[0] + rss[1] + rss[2] + rss[3];
        float mean = S * (1.f / 16384.f);
        float var  = SS * (1.f / 16384.f) - mean * mean;
        stats[2 * bg]     = mean;
        stats[2 * bg + 1] = rsqrtf(var + EPS);
    }
}

// ---------------------------------------------------------------------------
// GN apply + transpose: x (B,512,1024) fp32 -> xnT (B,1024,512) bf16
// ---------------------------------------------------------------------------
__global__ __launch_bounds__(256) void gn_apply_t(const float* __restrict__ x,
                                                  const float* __restrict__ stats,
                                                  const float* __restrict__ gamma,
                                                  const float* __restrict__ beta,
                                                  bf16* __restrict__ xnT)
{
    __shared__ bf16 tile[32][36];
    const int b = blockIdx.z, c0 = blockIdx.y * 32, i0 = blockIdx.x * 32;
    {
        const int cc = threadIdx.x >> 3;
        const int i4 = (threadIdx.x & 7) << 2;
        const int c  = c0 + cc;
        const float mean = stats[2 * ((b << 5) + (c >> 4))];
        const float rstd = stats[2 * ((b << 5) + (c >> 4)) + 1];
        const float a  = gamma[c] * rstd;
        const float bb = beta[c] - mean * a;
        float4 v = *(const float4*)(x + (((size_t)(b * 512 + c)) << 10) + i0 + i4);
        tile[cc][i4 + 0] = __float2bfloat16(v.x * a + bb);
        tile[cc][i4 + 1] = __float2bfloat16(v.y * a + bb);
        tile[cc][i4 + 2] = __float2bfloat16(v.z * a + bb);
        tile[cc][i4 + 3] = __float2bfloat16(v.w * a + bb);
    }
    __syncthreads();
    {
        const int ii = threadIdx.x >> 3;
        const int c4 = (threadIdx.x & 7) << 2;
        union { bf16 h[4]; uint2 u; } pk;
        pk.h[0] = tile[c4 + 0][ii];
        pk.h[1] = tile[c4 + 1][ii];
        pk.h[2] = tile[c4 + 2][ii];
        pk.h[3] = tile[c4 + 3][ii];
        *((uint2*)(xnT + (((size_t)(b * 1024 + i0 + ii)) << 9) + c0 + c4)) = pk.u;
    }
}

// ---------------------------------------------------------------------------
// prep: convert 4 weight matrices fp32->bf16 (blocks 0..1023) and build the
// concatenated qkv bias (block 1024).
// ---------------------------------------------------------------------------
__global__ __launch_bounds__(256) void prep(
    const float* __restrict__ wq, const float* __restrict__ wk,
    const float* __restrict__ wv, const float* __restrict__ wp,
    bf16* __restrict__ wqkvb, bf16* __restrict__ wpb,
    const float* __restrict__ bq, const float* __restrict__ bk,
    const float* __restrict__ bv, float* __restrict__ bqkv)
{
    const int id = blockIdx.x;
    if (id < 1024) {
        const int w = id >> 8;
        const float* src = (w == 0) ? wq : (w == 1) ? wk : (w == 2) ? wv : wp;
        bf16* dst = (w < 3) ? (wqkvb + (size_t)w * 262144) : wpb;
        const int g = (id & 255) * 256 + threadIdx.x;
        float4 v = ((const float4*)src)[g];
        union { bf16 h[4]; uint2 u; } pk;
        pk.h[0] = __float2bfloat16(v.x);
        pk.h[1] = __float2bfloat16(v.y);
        pk.h[2] = __float2bfloat16(v.z);
        pk.h[3] = __float2bfloat16(v.w);
        ((uint2*)dst)[g] = pk.u;
    } else {
        for (int t = threadIdx.x; t < 1536; t += 256)
            bqkv[t] = (t < 512) ? bq[t] : (t < 1024) ? bk[t - 512] : bv[t - 1024];
    }
}

// ---------------------------------------------------------------------------
extern "C" void kernel_launch(void* const* d_in, const int* in_sizes, int n_in,
                              void* d_out, int out_size, void* d_ws, size_t ws_size,
                              hipStream_t stream)
{
    const float* x     = (const float*)d_in[0];
    const float* gamma = (const float*)d_in[1];
    const float* beta  = (const float*)d_in[2];
    const float* wq    = (const float*)d_in[3];
    const float* bq    = (const float*)d_in[4];
    const float* wk    = (const float*)d_in[5];
    const float* bk    = (const float*)d_in[6];
    const float* wv    = (const float*)d_in[7];
    const float* bv    = (const float*)d_in[8];
    const float* wp    = (const float*)d_in[9];
    const float* bp    = (const float*)d_in[10];
    float* out = (float*)d_out;

    char* ws = (char*)d_ws;
    size_t off = 0;
    auto alloc = [&](size_t bytes) -> char* {
        char* p = ws + off;
        off += (bytes + 255) & ~(size_t)255;
        return p;
    };

    const long long S  = 1024, C = 512;
    const long long BS = S * C;           // per-batch elems of x/v/O2/xnT
    const long long ES = S * S;           // per-batch elems of qkT/P

    float* stats  = (float*)alloc(512 * 2 * sizeof(float));
    float* bqkv   = (float*)alloc(1536 * sizeof(float));
    float* rowsum = (float*)alloc((size_t)16 * S * sizeof(float));
    bf16* wqkvb = (bf16*)alloc((size_t)3 * C * C * 2);  // [wq; wk; wv]
    bf16* wpb   = (bf16*)alloc((size_t)C * C * 2);
    bf16* xnT   = (bf16*)alloc((size_t)16 * BS * 2);
    bf16* qkT   = (bf16*)alloc((size_t)16 * ES * 2);    // (B,1024,1024): [qT|kT]
    bf16* vv    = (bf16*)alloc((size_t)16 * BS * 2);    // (B,512,1024) c-major rows
    bf16* O2    = (bf16*)alloc((size_t)16 * BS * 2);

    int CB = 16;
    while (CB > 1 && off + (size_t)CB * ES * 2 + 1024 > ws_size) CB >>= 1;
    bf16* P = (bf16*)alloc((size_t)CB * ES * 2);

    prep<<<1025, 256, 0, stream>>>(wq, wk, wv, wp, wqkvb, wpb, bq, bk, bv, bqkv);
    hipMemsetAsync(rowsum, 0, (size_t)16 * S * sizeof(float), stream);

    gn_stats<<<512, 256, 0, stream>>>(x, stats);
    gn_apply_t<<<dim3(32, 16, 16), 256, 0, stream>>>(x, stats, gamma, beta, xnT);

    // QKV proj: M=1024 (i), N=1536 ([q|k|v]), K=512, Z=16.
    // n<1024 -> qkT[i][o]; n>=1024 -> vv[o'][j] transposed store.
    gemm_nt<2, 0, 0, 0, 0, 1, bf16><<<1536, 256, 0, stream>>>(
        xnT, BS, 512, wqkvb, 0, 512, qkT, ES, 1024, vv, BS,
        bqkv, nullptr, 0, 0, nullptr, 0, 512, 1.f, /*tpb*/96, /*gx*/12);

    const float scale = 0.044194173824159216f; // 512^-0.5
    for (int b0 = 0; b0 < 16; b0 += CB) {
        // P[i][j] = exp(scale * q_i.k_j); rowsum[i] += (atomics)
        gemm_nt<0, 1, 0, 1, 0, 0, bf16><<<CB * 64, 256, 0, stream>>>(
            qkT + (size_t)b0 * ES, ES, 1024,
            qkT + (size_t)b0 * ES + 512, ES, 1024,
            P, ES, 1024, nullptr, 0,
            nullptr, nullptr, 0, 0, rowsum + (size_t)b0 * S, (int)S,
            512, scale, /*tpb*/64, /*gx*/8);
        // O2[i][c] = (sum_j P[i][j] vv[c][j]) / rowsum[i]
        gemm_nt<0, 0, 0, 0, 1, 0, bf16><<<CB * 32, 256, 0, stream>>>(
            P, ES, 1024,
            vv + (size_t)b0 * BS, BS, 1024,
            O2 + (size_t)b0 * BS, BS, 512, nullptr, 0,
            nullptr, nullptr, 0, 0, rowsum + (size_t)b0 * S, (int)S,
            1024, 1.f, /*tpb*/32, /*gx*/4);
    }

    // out[o][i] = sum_c wp[o][c] O2[i][c] + bp[o] + x[o][i]
    gemm_nt<1, 0, 1, 0, 0, 0, float><<<512, 256, 0, stream>>>(
        wpb, 0, 512, O2, BS, 512, out, BS, 1024, nullptr, 0,
        bp, x, BS, 1024, nullptr, 0, 512, 1.f, /*tpb*/32, /*gx*/8);
}

// Round 5
// 282.507 us; speedup vs baseline: 1.1348x; 1.0386x over previous
//
#include <hip/hip_runtime.h>
#include <hip/hip_bf16.h>

using bf16 = __hip_bfloat16;

typedef __attribute__((ext_vector_type(8))) __bf16 bf16x8;
typedef __attribute__((ext_vector_type(4))) float floatx4;

#define EPS 1e-6f

#define RAW_BARRIER()  asm volatile("s_barrier" ::: "memory")
#define WAIT_VM6()     asm volatile("s_waitcnt vmcnt(6)" ::: "memory")
#define WAIT_VM4()     asm volatile("s_waitcnt vmcnt(4)" ::: "memory")
#define WAIT_VM0()     asm volatile("s_waitcnt vmcnt(0)" ::: "memory")

__device__ __forceinline__ void load_lds16(const void* g, void* l) {
    __builtin_amdgcn_global_load_lds(
        (const __attribute__((address_space(1))) void*)g,
        (__attribute__((address_space(3))) void*)l, 16, 0, 0);
}

__device__ __forceinline__ void storeOut(float* p, float v) { *p = v; }
__device__ __forceinline__ void storeOut(bf16* p, float v) { *p = __float2bfloat16(v); }

// ---------------------------------------------------------------------------
// Canonical NT GEMM: D[m][n] = sum_k A[m][k] * B[n][k]
// BM x 128 block tile, BK=32, double-buffered LDS, manual vmcnt pipeline.
// BM=256: wave tile 128x64 (8x4 MFMA, 128 acc VGPRs) - high arithmetic
//         intensity (43.7 FLOP/LDS-byte) for the big GEMMs.
// BM=128: wave tile 64x64 (4x4) - for dispatches that need >=2 blocks/CU.
// 1-D grid, XCD-aware decode (id&7 = XCD slot -> contiguous work chunk).
// QKV: n0>=1024 -> store transposed into vout (vv[c][j]).
// ---------------------------------------------------------------------------
template <int BM, int BIAS_MODE, int SCALE_EN, int RESID_EN, int EXP_MODE,
          int ROWDIV, int QKV, typename OutT>
__global__ __launch_bounds__(256, 2) void gemm_nt(
    const bf16* __restrict__ A, long long aStride, int lda,
    const bf16* __restrict__ B, long long bStride, int ldb,
    OutT* __restrict__ D, long long dStride, int ldd,
    bf16* __restrict__ vout, long long vStride,
    const float* __restrict__ bias,
    const float* __restrict__ resid, long long rStride, int ldr,
    float* __restrict__ rowsum, int rsStride,
    int K, float scale, int tpb, int gx)
{
    constexpr int MI = BM / 32;          // m-frags per wave (4 or 8)
    constexpr int NLA = BM / 64;         // A stage calls (2 or 4)
    constexpr int NL = NLA + 2;          // loads per stage

    __shared__ bf16 As[2][BM * 32];
    __shared__ bf16 Bs[2][128 * 32];

    const unsigned chunk = gridDim.x >> 3;
    const unsigned glob  = (blockIdx.x & 7) * chunk + (blockIdx.x >> 3);
    const unsigned z  = glob / (unsigned)tpb;
    const unsigned t  = glob % (unsigned)tpb;
    const int m0 = (int)(t / (unsigned)gx) * BM;
    const int n0 = (int)(t % (unsigned)gx) << 7;

    const int tid  = threadIdx.x;
    const int lane = tid & 63;
    const int wave = tid >> 6;
    const int wm   = wave >> 1;
    const int wn   = wave & 1;

    const bf16* Ab = A + (size_t)z * aStride + (size_t)m0 * lda;
    const bf16* Bb = B + (size_t)z * bStride + (size_t)n0 * ldb;

    floatx4 acc[MI][4];
#pragma unroll
    for (int i = 0; i < MI; ++i)
#pragma unroll
        for (int j = 0; j < 4; ++j) acc[i][j] = (floatx4){0.f, 0.f, 0.f, 0.f};

    const int laneRow = lane & 15;
    const int laneKq  = lane >> 4;

    auto stage = [&](int kt) {
        const int k0 = kt << 5;
        char* Ad = (char*)As[kt & 1];
        char* Bd = (char*)Bs[kt & 1];
#pragma unroll
        for (int t4 = 0; t4 < NLA; ++t4) {
            const int idx = tid + t4 * 256;
            const int r = idx & (BM - 1), q = idx / BM;
            load_lds16(Ab + (size_t)r * lda + k0 + q * 8, Ad + idx * 16);
        }
#pragma unroll
        for (int t4 = 0; t4 < 2; ++t4) {
            const int idx = tid + t4 * 256;
            const int r = idx & 127, q = idx >> 7;
            load_lds16(Bb + (size_t)r * ldb + k0 + q * 8, Bd + idx * 16);
        }
    };

    const int kIters = K >> 5;
    stage(0);
    stage(1);
    for (int kt = 0; kt < kIters; ++kt) {
        if (kt + 1 < kIters) {
            if (NL == 6) { WAIT_VM6(); } else { WAIT_VM4(); }
        } else {
            WAIT_VM0();
        }
        RAW_BARRIER();

        const char* AsB = (const char*)As[kt & 1];
        const char* BsB = (const char*)Bs[kt & 1];
        bf16x8 af[MI], bfr[4];
#pragma unroll
        for (int im = 0; im < MI; ++im)
            af[im] = *(const bf16x8*)(AsB +
                (laneKq * BM + wm * (BM / 2) + im * 16 + laneRow) * 16);
#pragma unroll
        for (int in = 0; in < 4; ++in)
            bfr[in] = *(const bf16x8*)(BsB +
                (laneKq * 128 + wn * 64 + in * 16 + laneRow) * 16);
#pragma unroll
        for (int im = 0; im < MI; ++im)
#pragma unroll
            for (int in = 0; in < 4; ++in)
                acc[im][in] = __builtin_amdgcn_mfma_f32_16x16x32_bf16(
                    af[im], bfr[in], acc[im][in], 0, 0, 0);

        RAW_BARRIER();
        if (kt + 2 < kIters) stage(kt + 2);
    }

    // Epilogue. C/D frag layout: col = lane&15, row = (lane>>4)*4 + reg
    const size_t dbase = (size_t)z * dStride;
#pragma unroll
    for (int im = 0; im < MI; ++im) {
        const int gmb = m0 + wm * (BM / 2) + im * 16 + (laneKq << 2);
        float ri[4];
        if (ROWDIV) {
#pragma unroll
            for (int r = 0; r < 4; ++r)
                ri[r] = 1.f / rowsum[(size_t)z * rsStride + gmb + r];
        }
        float rsum[4] = {0.f, 0.f, 0.f, 0.f};
#pragma unroll
        for (int in = 0; in < 4; ++in) {
            const int gn = n0 + wn * 64 + in * 16 + laneRow;
            float bn = 0.f;
            if (BIAS_MODE == 2) bn = bias[gn];
            if (QKV && n0 >= 1024) {
                union { bf16 h[4]; ushort4 u; } pk;
#pragma unroll
                for (int r = 0; r < 4; ++r)
                    pk.h[r] = __float2bfloat16(acc[im][in][r] + bn);
                *(ushort4*)(vout + (size_t)z * vStride +
                            (size_t)(gn - 1024) * 1024 + gmb) = pk.u;
            } else {
#pragma unroll
                for (int r = 0; r < 4; ++r) {
                    const int gm = gmb + r;
                    float v = acc[im][in][r];
                    if (SCALE_EN) v *= scale;
                    if (EXP_MODE) { v = __expf(v); rsum[r] += v; }
                    if (ROWDIV) v *= ri[r];
                    if (BIAS_MODE == 1) v += bias[gm];
                    if (BIAS_MODE == 2) v += bn;
                    if (RESID_EN)
                        v += resid[(size_t)z * rStride + (size_t)gm * ldr + gn];
                    storeOut(D + dbase + (size_t)gm * ldd + gn, v);
                }
            }
        }
        if (EXP_MODE) {
#pragma unroll
            for (int r = 0; r < 4; ++r) {
                float s = rsum[r];
                s += __shfl_xor(s, 1);
                s += __shfl_xor(s, 2);
                s += __shfl_xor(s, 4);
                s += __shfl_xor(s, 8);
                if (laneRow == 0)
                    atomicAdd(rowsum + (size_t)z * rsStride + gmb + r, s);
            }
        }
    }
}

// ---------------------------------------------------------------------------
// GroupNorm stats: one block per (b, g); 16 ch x 1024 = 16384 contiguous floats
// ---------------------------------------------------------------------------
__global__ __launch_bounds__(256) void gn_stats(const float* __restrict__ x,
                                                float* __restrict__ stats)
{
    const int bg = blockIdx.x;
    const float4* p = (const float4*)(x + (size_t)bg * 16384);
    float s = 0.f, ss = 0.f;
    for (int i = threadIdx.x; i < 4096; i += 256) {
        float4 v = p[i];
        s  += v.x + v.y + v.z + v.w;
        ss += v.x * v.x + v.y * v.y + v.z * v.z + v.w * v.w;
    }
#pragma unroll
    for (int off = 32; off; off >>= 1) {
        s  += __shfl_down(s, off);
        ss += __shfl_down(ss, off);
    }
    __shared__ float rs[4], rss[4];
    const int wv = threadIdx.x >> 6;
    if ((threadIdx.x & 63) == 0) { rs[wv] = s; rss[wv] = ss; }
    __syncthreads();
    if (threadIdx.x == 0) {
        float S  = rs[0] + rs[1] + rs[2] + rs[3];
        float SS = rss[0] + rss[1] + rss[2] + rss[3];
        float mean = S * (1.f / 16384.f);
        float var  = SS * (1.f / 16384.f) - mean * mean;
        stats[2 * bg]     = mean;
        stats[2 * bg + 1] = rsqrtf(var + EPS);
    }
}

// ---------------------------------------------------------------------------
// GN apply + transpose: x (B,512,1024) fp32 -> xnT (B,1024,512) bf16
// ---------------------------------------------------------------------------
__global__ __launch_bounds__(256) void gn_apply_t(const float* __restrict__ x,
                                                  const float* __restrict__ stats,
                                                  const float* __restrict__ gamma,
                                                  const float* __restrict__ beta,
                                                  bf16* __restrict__ xnT)
{
    __shared__ bf16 tile[32][36];
    const int b = blockIdx.z, c0 = blockIdx.y * 32, i0 = blockIdx.x * 32;
    {
        const int cc = threadIdx.x >> 3;
        const int i4 = (threadIdx.x & 7) << 2;
        const int c  = c0 + cc;
        const float mean = stats[2 * ((b << 5) + (c >> 4))];
        const float rstd = stats[2 * ((b << 5) + (c >> 4)) + 1];
        const float a  = gamma[c] * rstd;
        const float bb = beta[c] - mean * a;
        float4 v = *(const float4*)(x + (((size_t)(b * 512 + c)) << 10) + i0 + i4);
        tile[cc][i4 + 0] = __float2bfloat16(v.x * a + bb);
        tile[cc][i4 + 1] = __float2bfloat16(v.y * a + bb);
        tile[cc][i4 + 2] = __float2bfloat16(v.z * a + bb);
        tile[cc][i4 + 3] = __float2bfloat16(v.w * a + bb);
    }
    __syncthreads();
    {
        const int ii = threadIdx.x >> 3;
        const int c4 = (threadIdx.x & 7) << 2;
        union { bf16 h[4]; uint2 u; } pk;
        pk.h[0] = tile[c4 + 0][ii];
        pk.h[1] = tile[c4 + 1][ii];
        pk.h[2] = tile[c4 + 2][ii];
        pk.h[3] = tile[c4 + 3][ii];
        *((uint2*)(xnT + (((size_t)(b * 1024 + i0 + ii)) << 9) + c0 + c4)) = pk.u;
    }
}

// ---------------------------------------------------------------------------
// prep: weights fp32->bf16 (blocks 0..1023), qkv bias concat (block 1024),
// rowsum zero (block 1025).
// ---------------------------------------------------------------------------
__global__ __launch_bounds__(256) void prep(
    const float* __restrict__ wq, const float* __restrict__ wk,
    const float* __restrict__ wv, const float* __restrict__ wp,
    bf16* __restrict__ wqkvb, bf16* __restrict__ wpb,
    const float* __restrict__ bq, const float* __restrict__ bk,
    const float* __restrict__ bv, float* __restrict__ bqkv,
    float* __restrict__ rowsum)
{
    const int id = blockIdx.x;
    if (id < 1024) {
        const int w = id >> 8;
        const float* src = (w == 0) ? wq : (w == 1) ? wk : (w == 2) ? wv : wp;
        bf16* dst = (w < 3) ? (wqkvb + (size_t)w * 262144) : wpb;
        const int g = (id & 255) * 256 + threadIdx.x;
        float4 v = ((const float4*)src)[g];
        union { bf16 h[4]; uint2 u; } pk;
        pk.h[0] = __float2bfloat16(v.x);
        pk.h[1] = __float2bfloat16(v.y);
        pk.h[2] = __float2bfloat16(v.z);
        pk.h[3] = __float2bfloat16(v.w);
        ((uint2*)dst)[g] = pk.u;
    } else if (id == 1024) {
        for (int t = threadIdx.x; t < 1536; t += 256)
            bqkv[t] = (t < 512) ? bq[t] : (t < 1024) ? bk[t - 512] : bv[t - 1024];
    } else {
        float4 zero = {0.f, 0.f, 0.f, 0.f};
#pragma unroll
        for (int j = 0; j < 16; ++j)
            ((float4*)rowsum)[threadIdx.x + j * 256] = zero;
    }
}

// ---------------------------------------------------------------------------
extern "C" void kernel_launch(void* const* d_in, const int* in_sizes, int n_in,
                              void* d_out, int out_size, void* d_ws, size_t ws_size,
                              hipStream_t stream)
{
    const float* x     = (const float*)d_in[0];
    const float* gamma = (const float*)d_in[1];
    const float* beta  = (const float*)d_in[2];
    const float* wq    = (const float*)d_in[3];
    const float* bq    = (const float*)d_in[4];
    const float* wk    = (const float*)d_in[5];
    const float* bk    = (const float*)d_in[6];
    const float* wv    = (const float*)d_in[7];
    const float* bv    = (const float*)d_in[8];
    const float* wp    = (const float*)d_in[9];
    const float* bp    = (const float*)d_in[10];
    float* out = (float*)d_out;

    char* ws = (char*)d_ws;
    size_t off = 0;
    auto alloc = [&](size_t bytes) -> char* {
        char* p = ws + off;
        off += (bytes + 255) & ~(size_t)255;
        return p;
    };

    const long long S  = 1024, C = 512;
    const long long BS = S * C;
    const long long ES = S * S;

    float* stats  = (float*)alloc(512 * 2 * sizeof(float));
    float* bqkv   = (float*)alloc(1536 * sizeof(float));
    float* rowsum = (float*)alloc((size_t)16 * S * sizeof(float));
    bf16* wqkvb = (bf16*)alloc((size_t)3 * C * C * 2);  // [wq; wk; wv]
    bf16* wpb   = (bf16*)alloc((size_t)C * C * 2);
    bf16* xnT   = (bf16*)alloc((size_t)16 * BS * 2);
    bf16* qkT   = (bf16*)alloc((size_t)16 * ES * 2);    // (B,1024,1024): [qT|kT]
    bf16* vv    = (bf16*)alloc((size_t)16 * BS * 2);    // (B,512,1024)
    bf16* O2    = (bf16*)alloc((size_t)16 * BS * 2);

    int CB = 16;
    while (CB > 1 && off + (size_t)CB * ES * 2 + 1024 > ws_size) CB >>= 1;
    bf16* P = (bf16*)alloc((size_t)CB * ES * 2);

    prep<<<1026, 256, 0, stream>>>(wq, wk, wv, wp, wqkvb, wpb, bq, bk, bv,
                                   bqkv, rowsum);

    gn_stats<<<512, 256, 0, stream>>>(x, stats);
    gn_apply_t<<<dim3(32, 16, 16), 256, 0, stream>>>(x, stats, gamma, beta, xnT);

    // QKV proj: M=1024 (i), N=1536 ([q|k|v]), K=512, Z=16. BM=256.
    gemm_nt<256, 2, 0, 0, 0, 0, 1, bf16><<<768, 256, 0, stream>>>(
        xnT, BS, 512, wqkvb, 0, 512, qkT, ES, 1024, vv, BS,
        bqkv, nullptr, 0, 0, nullptr, 0, 512, 1.f, /*tpb*/48, /*gx*/12);

    const float scale = 0.044194173824159216f; // 512^-0.5
    for (int b0 = 0; b0 < 16; b0 += CB) {
        // P[i][j] = exp(scale * q_i.k_j); rowsum[i] += (atomics). BM=256.
        gemm_nt<256, 0, 1, 0, 1, 0, 0, bf16><<<CB * 32, 256, 0, stream>>>(
            qkT + (size_t)b0 * ES, ES, 1024,
            qkT + (size_t)b0 * ES + 512, ES, 1024,
            P, ES, 1024, nullptr, 0,
            nullptr, nullptr, 0, 0, rowsum + (size_t)b0 * S, (int)S,
            512, scale, /*tpb*/32, /*gx*/8);
        // O2[i][c] = (sum_j P[i][j] vv[c][j]) / rowsum[i]. BM=128 (2 blk/CU).
        gemm_nt<128, 0, 0, 0, 0, 1, 0, bf16><<<CB * 32, 256, 0, stream>>>(
            P, ES, 1024,
            vv + (size_t)b0 * BS, BS, 1024,
            O2 + (size_t)b0 * BS, BS, 512, nullptr, 0,
            nullptr, nullptr, 0, 0, rowsum + (size_t)b0 * S, (int)S,
            1024, 1.f, /*tpb*/32, /*gx*/4);
    }

    // out[o][i] = sum_c wp[o][c] O2[i][c] + bp[o] + x[o][i]. BM=128.
    gemm_nt<128, 1, 0, 1, 0, 0, 0, float><<<512, 256, 0, stream>>>(
        wpb, 0, 512, O2, BS, 512, out, BS, 1024, nullptr, 0,
        bp, x, BS, 1024, nullptr, 0, 512, 1.f, /*tpb*/32, /*gx*/8);
}